// Round 1
// baseline (286.995 us; speedup 1.0000x reference)
//
#include <hip/hip_runtime.h>
#include <math.h>

#define B_    2048
#define M_    200
#define DQ_   512
#define DT_   768
#define DA_   64
#define NEG_INF_ (-1e30f)

__device__ __forceinline__ float dot4(float4 a, float4 b) {
    return a.x * b.x + a.y * b.y + a.z * b.z + a.w * b.w;
}

__device__ __forceinline__ void fma4(float4& a, float e, float4 c) {
    a.x += e * c.x; a.y += e * c.y; a.z += e * c.z; a.w += e * c.w;
}

__device__ __forceinline__ void scale_add4(float4& a, float sc, float4 c) {
    a.x = a.x * sc + c.x; a.y = a.y * sc + c.y;
    a.z = a.z * sc + c.z; a.w = a.w * sc + c.w;
}

// One block per batch element b.
// Algebraic rewrite:
//   scores[b,m] = desc[b,m,:] . w[b]            where w[b] = Wk @ (U^T applied... w[t] = sum_d Wk[t,d]*QU[d])
//   context[b]  = (softmax-weighted sum of desc rows) @ Wv   (online softmax, V never materialized)
__global__ __launch_bounds__(256, 4)
void bilinear_attn_fused(const float* __restrict__ q_vec,
                         const float* __restrict__ desc,
                         const int*   __restrict__ mask,
                         const float* __restrict__ Wq,
                         const float* __restrict__ Wk,
                         const float* __restrict__ Wv,
                         const float* __restrict__ U,
                         const float* __restrict__ Wo,
                         const float* __restrict__ bo,
                         float* __restrict__ out_fused,
                         float* __restrict__ out_attn)
{
    const int b    = blockIdx.x;
    const int tid  = threadIdx.x;
    const int lane = tid & 63;
    const int wave = tid >> 6;

    __shared__ float s_qv[DQ_];          // staged q_vec row (kept through epilogue)
    __shared__ float s_red[256];         // cross-wave reduction scratch
    __shared__ float s_Q[DA_];
    __shared__ float s_QU[DA_];
    __shared__ float s_w[DT_];           // w[b] vector
    __shared__ float s_scores[M_];
    __shared__ float s_wm[4];
    __shared__ float s_wl[4];
    __shared__ float s_acc[4][DT_];      // per-wave weighted-sum accumulators
    __shared__ float s_ctx[DA_];

    // ---- stage q_vec row ----
    const float* qrow = q_vec + (size_t)b * DQ_;
    for (int i = tid; i < DQ_; i += 256) s_qv[i] = qrow[i];
    __syncthreads();

    // ---- Q = qv @ Wq  (64 outputs, 4-way split over t) ----
    {
        const int d = lane;          // output dim: coalesced Wq reads across lanes
        const int t0 = wave * (DQ_ / 4);
        float p = 0.f;
        for (int t = t0; t < t0 + DQ_ / 4; ++t)
            p += s_qv[t] * Wq[t * DA_ + d];
        s_red[tid] = p;
    }
    __syncthreads();
    if (tid < DA_)
        s_Q[tid] = s_red[tid] + s_red[tid + 64] + s_red[tid + 128] + s_red[tid + 192];
    __syncthreads();

    // ---- QU = Q @ U ----
    if (tid < DA_) {
        float qu = 0.f;
        for (int e = 0; e < DA_; ++e) qu += s_Q[e] * U[e * DA_ + tid];
        s_QU[tid] = qu;
    }
    __syncthreads();

    // ---- w[t] = sum_d QU[d] * Wk[t,d] ----
    for (int t = tid; t < DT_; t += 256) {
        const float4* wk4 = reinterpret_cast<const float4*>(Wk + (size_t)t * DA_);
        const float4* qu4 = reinterpret_cast<const float4*>(s_QU);
        float a = 0.f;
        #pragma unroll
        for (int i = 0; i < DA_ / 4; ++i) a += dot4(wk4[i], qu4[i]);
        s_w[t] = a;
    }
    __syncthreads();

    // per-lane slice of w (positions lane*4 + 256*j, j=0..2)
    const int off0 = lane * 4, off1 = lane * 4 + 256, off2 = lane * 4 + 512;
    const float4 wv0 = *reinterpret_cast<const float4*>(&s_w[off0]);
    const float4 wv1 = *reinterpret_cast<const float4*>(&s_w[off1]);
    const float4 wv2 = *reinterpret_cast<const float4*>(&s_w[off2]);

    // ---- stream desc rows: online softmax + weighted token sum ----
    const float* descb = desc + (size_t)b * M_ * DT_;
    const int*   maskb = mask + (size_t)b * M_;

    float4 acc0 = {0,0,0,0}, acc1 = {0,0,0,0}, acc2 = {0,0,0,0};
    float mw = -INFINITY, lw = 0.f;

    float4 c0, c1, c2;
    {
        const float* r = descb + (size_t)wave * DT_;
        c0 = *reinterpret_cast<const float4*>(r + off0);
        c1 = *reinterpret_cast<const float4*>(r + off1);
        c2 = *reinterpret_cast<const float4*>(r + off2);
    }
    for (int row = wave; row < M_; row += 4) {
        // prefetch next row for this wave
        float4 n0 = {0,0,0,0}, n1 = {0,0,0,0}, n2 = {0,0,0,0};
        const int nrow = row + 4;
        if (nrow < M_) {
            const float* r = descb + (size_t)nrow * DT_;
            n0 = *reinterpret_cast<const float4*>(r + off0);
            n1 = *reinterpret_cast<const float4*>(r + off1);
            n2 = *reinterpret_cast<const float4*>(r + off2);
        }
        // score = desc_row . w  (wave-wide reduce)
        float p = dot4(c0, wv0) + dot4(c1, wv1) + dot4(c2, wv2);
        #pragma unroll
        for (int o = 32; o >= 1; o >>= 1) p += __shfl_xor(p, o, 64);
        const float s = (maskb[row] == 0) ? NEG_INF_ : p;
        if (lane == 0) s_scores[row] = s;

        // online softmax update (branch is wave-uniform: s is uniform)
        if (s <= mw) {
            const float e = __expf(s - mw);
            lw += e;
            fma4(acc0, e, c0); fma4(acc1, e, c1); fma4(acc2, e, c2);
        } else {
            const float sc = __expf(mw - s);
            lw = lw * sc + 1.f;
            scale_add4(acc0, sc, c0); scale_add4(acc1, sc, c1); scale_add4(acc2, sc, c2);
            mw = s;
        }
        c0 = n0; c1 = n1; c2 = n2;
    }

    if (lane == 0) { s_wm[wave] = mw; s_wl[wave] = lw; }
    *reinterpret_cast<float4*>(&s_acc[wave][off0]) = acc0;
    *reinterpret_cast<float4*>(&s_acc[wave][off1]) = acc1;
    *reinterpret_cast<float4*>(&s_acc[wave][off2]) = acc2;
    __syncthreads();

    // ---- merge 4 wave states ----
    const float m0 = s_wm[0], m1 = s_wm[1], m2 = s_wm[2], m3 = s_wm[3];
    const float Mx = fmaxf(fmaxf(m0, m1), fmaxf(m2, m3));
    const float f0 = __expf(m0 - Mx), f1 = __expf(m1 - Mx);
    const float f2 = __expf(m2 - Mx), f3 = __expf(m3 - Mx);
    const float ltot  = s_wl[0] * f0 + s_wl[1] * f1 + s_wl[2] * f2 + s_wl[3] * f3;
    const float inv_l = 1.0f / ltot;   // ltot >= 1 always (max-holding wave contributes >= 1)

    // normalized weighted token sum -> s_acc[0][.]
    for (int t = tid; t < DT_; t += 256) {
        const float v = s_acc[0][t] * f0 + s_acc[1][t] * f1
                      + s_acc[2][t] * f2 + s_acc[3][t] * f3;
        s_acc[0][t] = v * inv_l;
    }
    // attn output
    for (int r = tid; r < M_; r += 256)
        out_attn[(size_t)b * M_ + r] = __expf(s_scores[r] - Mx) * inv_l;
    __syncthreads();

    // ---- ctx[d] = sum_t sbar[t] * Wv[t,d] ----
    {
        const int d  = lane;                 // coalesced Wv reads across lanes
        const int t0 = wave * (DT_ / 4);     // 192 t's per wave
        float cp = 0.f;
        for (int t = t0; t < t0 + DT_ / 4; ++t)
            cp += s_acc[0][t] * Wv[(size_t)t * DA_ + d];
        s_red[tid] = cp;
    }
    __syncthreads();
    if (tid < DA_)
        s_ctx[tid] = s_red[tid] + s_red[tid + 64] + s_red[tid + 128] + s_red[tid + 192];
    __syncthreads();

    // ---- fused = ctx @ Wo + bo + q_vec ----
    for (int j = tid; j < DQ_; j += 256) {
        float f = bo[j] + s_qv[j];
        #pragma unroll 8
        for (int d = 0; d < DA_; ++d)
            f += s_ctx[d] * Wo[(size_t)d * DQ_ + j];
        out_fused[(size_t)b * DQ_ + j] = f;
    }
}

extern "C" void kernel_launch(void* const* d_in, const int* in_sizes, int n_in,
                              void* d_out, int out_size, void* d_ws, size_t ws_size,
                              hipStream_t stream) {
    (void)in_sizes; (void)n_in; (void)d_ws; (void)ws_size; (void)out_size;

    const float* q_vec = (const float*)d_in[0];
    const float* desc  = (const float*)d_in[1];
    const int*   mask  = (const int*)  d_in[2];
    const float* Wq    = (const float*)d_in[3];
    const float* Wk    = (const float*)d_in[4];
    const float* Wv    = (const float*)d_in[5];
    const float* U     = (const float*)d_in[6];
    const float* Wo    = (const float*)d_in[7];
    const float* bo    = (const float*)d_in[8];

    float* out_fused = (float*)d_out;                     // (B, DQ)
    float* out_attn  = (float*)d_out + (size_t)B_ * DQ_;  // (B, M)

    bilinear_attn_fused<<<dim3(B_), dim3(256), 0, stream>>>(
        q_vec, desc, mask, Wq, Wk, Wv, U, Wo, bo, out_fused, out_attn);
}